// Round 8
// baseline (260.066 us; speedup 1.0000x reference)
//
#include <hip/hip_runtime.h>
#include <math.h>

#define NTOK 2048
#define DDIM 1024
#define NEXP 8
#define DFF 4096
#define TWODFF 8192

typedef __attribute__((ext_vector_type(8))) short bf16x8;
typedef __attribute__((ext_vector_type(4))) float f32x4;

__device__ __forceinline__ short f2bf(float f) {
  unsigned u = __builtin_bit_cast(unsigned, f);
  u = (u + 0x7FFFu + ((u >> 16) & 1u)) >> 16;
  return (short)u;
}

// packed f32 pair -> 2x bf16 (D.lo = a, D.hi = b), RTNE
__device__ __forceinline__ unsigned pk2(float a, float b) {
  unsigned r;
  asm("v_cvt_pk_bf16_f32 %0, %1, %2" : "=v"(r) : "v"(a), "v"(b));
  return r;
}

// ---------------- routing ----------------
__global__ void route_k(const float* __restrict__ disp, const float* __restrict__ comb,
                        int* __restrict__ cnt, int* __restrict__ tokl,
                        float* __restrict__ scale) {
  __shared__ int lcnt[NEXP];
  const int tid = threadIdx.x;
  if (tid < NEXP) lcnt[tid] = 0;
  __syncthreads();
  for (int i = 0; i < 8; ++i) {
    const int t = i * 256 + tid;
    const float* row = disp + (size_t)t * NEXP;
    int e = 0;
#pragma unroll
    for (int n = 1; n < NEXP; ++n) e = (row[n] > row[e]) ? n : e;
    const float p = comb[(size_t)t * NEXP + e];
    const int slot = atomicAdd(&lcnt[e], 1);
    tokl[e * NTOK + slot] = t;
    scale[t] = p;
  }
  __syncthreads();
  if (tid < NEXP) cnt[tid] = lcnt[tid];
}

// ---------------- GEMM1: act = x * gelu(gate), bf16 out ----------------
// r2 frame: BM=128 tok, BNf=64 dual (128 wrows), BK=32, 4 waves 2m x 2f,
// 2 LDS buffers, 4 blocks/CU. KEY CHANGE vs r2/r7: global loads issued at
// the TOP of the iteration (right after __syncthreads). __syncthreads drains
// vmcnt to 0, so bottom-issued loads get zero latency hiding; top-issued
// loads have a full MFMA+store phase of slack before the next barrier.
// Pipeline: tile t loaded at step t-2 (top), LDS-stored at step t-1 (bottom),
// consumed at step t. Tile t lives in register set t&1 and LDS buffer t&1.
#define G1_LOAD(aR, bR, k0) do {                                              \
  _Pragma("unroll") for (int i_ = 0; i_ < 4; ++i_) {                          \
    bR[i_] = *(const float4*)(bP[i_] + (k0));                                 \
    aR[i_] = aP[i_] ? *(const float4*)(aP[i_] + (k0))                         \
                    : make_float4(0.f, 0.f, 0.f, 0.f);                        \
  } } while (0)

#define G1_STORE(aR, bR, buf) do {                                            \
  _Pragma("unroll") for (int i_ = 0; i_ < 4; ++i_) {                          \
    const int row_ = i_ * 32 + r0;                                            \
    const int ba_ = (row_ * 64 + (tid & 7) * 8) ^ ((row_ & 7) << 4);          \
    uint2 va_, vb_;                                                           \
    va_.x = pk2(aR[i_].x, aR[i_].y); va_.y = pk2(aR[i_].z, aR[i_].w);         \
    vb_.x = pk2(bR[i_].x, bR[i_].y); vb_.y = pk2(bR[i_].z, bR[i_].w);         \
    *(uint2*)((char*)Al[buf] + ba_) = va_;                                    \
    *(uint2*)((char*)Bl[buf] + ba_) = vb_;                                    \
  } } while (0)

__global__ __launch_bounds__(256, 2) void gemm1_k(
    const float* __restrict__ hid, const float* __restrict__ Win,
    const float* __restrict__ bin, const int* __restrict__ cnt,
    const int* __restrict__ tokl, short* __restrict__ act) {
  const int e = blockIdx.z;
  const int Me = cnt[e];
  const int m0 = blockIdx.y * 128;
  if (m0 >= Me) return;
  const int f0 = blockIdx.x * 64;

  __shared__ short Al[2][128 * 32];  // 64 B rows, XOR-swizzled
  __shared__ short Bl[2][128 * 32];  // rows 0-63: x(f0..), 64-127: gate
  __shared__ int tokids[128];

  const int tid = threadIdx.x;
  if (tid < 128) {
    const int r = m0 + tid;
    tokids[tid] = (r < Me) ? tokl[e * NTOK + r] : -1;
  }
  __syncthreads();

  // staging: slot i -> row = i*32 + (tid>>3), col = (tid&7)*4 floats
  const int r0 = tid >> 3;
  const int c0 = (tid & 7) * 4;
  const float* aP[4];
  const float* bP[4];
#pragma unroll
  for (int i = 0; i < 4; ++i) {
    const int row = i * 32 + r0;
    const int tk = tokids[row];
    aP[i] = (tk >= 0) ? (hid + (size_t)tk * DDIM + c0) : nullptr;
    const int wr = (row < 64) ? (f0 + row) : (DFF + f0 + (row - 64));
    bP[i] = Win + (size_t)e * TWODFF * DDIM + (size_t)wr * DDIM + c0;
  }

  const int wid = tid >> 6, lane = tid & 63;
  const int wm = (wid >> 1) * 64;
  const int wf = (wid & 1) * 32;
  const int lr = lane & 15;
  const int kbyte = (lane >> 4) * 16;

  f32x4 accx[4][2], accg[4][2];
  const f32x4 zf = {0.f, 0.f, 0.f, 0.f};
#pragma unroll
  for (int a = 0; a < 4; ++a)
#pragma unroll
    for (int b = 0; b < 2; ++b) { accx[a][b] = zf; accg[a][b] = zf; }

  float4 aRa[4], bRa[4], aRb[4], bRb[4];
  // prologue: tile0 -> set a -> buf0; tile1 -> set b (in flight)
  G1_LOAD(aRa, bRa, 0);
  G1_STORE(aRa, bRa, 0);
  G1_LOAD(aRb, bRb, 32);

  for (int kt = 0; kt < 32; ++kt) {
    __syncthreads();
    // issue tile kt+2 FIRST (set kt&1 is free: tile kt was stored last step)
    if (kt < 30) {
      if (kt & 1) G1_LOAD(aRb, bRb, (kt + 2) * 32);
      else        G1_LOAD(aRa, bRa, (kt + 2) * 32);
    }
    const char* Ab = (const char*)Al[kt & 1];
    const char* Bb = (const char*)Bl[kt & 1];
    bf16x8 a[4], bx[2], bg[2];
#pragma unroll
    for (int fm = 0; fm < 4; ++fm) {
      const int row = wm + fm * 16 + lr;
      a[fm] = *(const bf16x8*)(Ab + ((row * 64 + kbyte) ^ ((row & 7) << 4)));
    }
#pragma unroll
    for (int ff = 0; ff < 2; ++ff) {
      const int rx = wf + ff * 16 + lr;
      bx[ff] = *(const bf16x8*)(Bb + ((rx * 64 + kbyte) ^ ((rx & 7) << 4)));
      const int rg = rx + 64;
      bg[ff] = *(const bf16x8*)(Bb + ((rg * 64 + kbyte) ^ ((rg & 7) << 4)));
    }
#pragma unroll
    for (int fm = 0; fm < 4; ++fm)
#pragma unroll
      for (int ff = 0; ff < 2; ++ff) {
        accx[fm][ff] = __builtin_amdgcn_mfma_f32_16x16x32_bf16(a[fm], bx[ff], accx[fm][ff], 0, 0, 0);
        accg[fm][ff] = __builtin_amdgcn_mfma_f32_16x16x32_bf16(a[fm], bg[ff], accg[fm][ff], 0, 0, 0);
      }
    // store tile kt+1 (loaded at step kt-1 -> ~full step of slack) -> buf (kt+1)&1
    if (kt < 31) {
      if (kt & 1) G1_STORE(aRa, bRa, (kt + 1) & 1);
      else        G1_STORE(aRb, bRb, (kt + 1) & 1);
    }
  }

  const int orb = (lane >> 4) * 4;
#pragma unroll
  for (int ff = 0; ff < 2; ++ff) {
    const int fcol = f0 + wf + ff * 16 + lr;
    const float bx_ = bin[e * TWODFF + fcol];
    const float bg_ = bin[e * TWODFF + DFF + fcol];
#pragma unroll
    for (int fm = 0; fm < 4; ++fm)
#pragma unroll
      for (int j = 0; j < 4; ++j) {
        const int row = wm + fm * 16 + orb + j;
        if (m0 + row < Me) {
          const float x = accx[fm][ff][j] + bx_;
          const float g = accg[fm][ff][j] + bg_;
          const float gl = 0.5f * g * (1.f + erff(g * 0.70710678118654752f));
          act[(size_t)tokids[row] * DFF + fcol] = f2bf(x * gl);
        }
      }
  }
}

// ---------------- GEMM2: out = p * (act @ W_out^T + b_out) ----------------
// r2 frame (BM=128, BN=64, BK=64, 256 thr, 2-buf LDS) with the same
// issue-at-top dist-2 pipeline.
#define G2_LOAD(aR, bR, k0) do {                                              \
  _Pragma("unroll") for (int i_ = 0; i_ < 4; ++i_)                            \
    bR[i_] = *(const float4*)(bP[i_] + (k0));                                 \
  _Pragma("unroll") for (int i_ = 0; i_ < 4; ++i_)                            \
    aR[i_] = aP[i_] ? *(const bf16x8*)(aP[i_] + (k0)) : zro;                  \
  } while (0)

#define G2_STORE(aR, bR, buf) do {                                            \
  _Pragma("unroll") for (int i_ = 0; i_ < 4; ++i_) {                          \
    const int row_ = i_ * 32 + ar0;                                           \
    const int ba_ = (row_ * 128 + (tid & 7) * 16) ^ ((row_ & 7) << 4);        \
    *(bf16x8*)((char*)Al[buf] + ba_) = aR[i_];                                \
  }                                                                           \
  _Pragma("unroll") for (int i_ = 0; i_ < 4; ++i_) {                          \
    const int row_ = i_ * 16 + br0;                                           \
    const int bb_ = (row_ * 128 + (tid & 15) * 8) ^ ((row_ & 7) << 4);        \
    uint2 vb_;                                                                \
    vb_.x = pk2(bR[i_].x, bR[i_].y); vb_.y = pk2(bR[i_].z, bR[i_].w);         \
    *(uint2*)((char*)Bl[buf] + bb_) = vb_;                                    \
  } } while (0)

__global__ __launch_bounds__(256, 2) void gemm2_k(
    const short* __restrict__ act, const float* __restrict__ Wout,
    const float* __restrict__ bout, const int* __restrict__ cnt,
    const int* __restrict__ tokl, const float* __restrict__ scale,
    float* __restrict__ out) {
  const int e = blockIdx.z;
  const int Me = cnt[e];
  const int m0 = blockIdx.y * 128;
  if (m0 >= Me) return;
  const int n0 = blockIdx.x * 64;

  __shared__ short Al[2][128 * 64];
  __shared__ short Bl[2][64 * 64];
  __shared__ int tokids[128];
  __shared__ float pv[128];

  const int tid = threadIdx.x;
  if (tid < 128) {
    const int r = m0 + tid;
    const int tk = (r < Me) ? tokl[e * NTOK + r] : -1;
    tokids[tid] = tk;
    pv[tid] = (tk >= 0) ? scale[tk] : 0.f;
  }
  __syncthreads();

  const int ar0 = tid >> 3;
  const int ac0 = (tid & 7) * 8;
  const short* aP[4];
#pragma unroll
  for (int i = 0; i < 4; ++i) {
    const int row = i * 32 + ar0;
    const int tk = tokids[row];
    aP[i] = (tk >= 0) ? (act + (size_t)tk * DFF + ac0) : nullptr;
  }
  const int br0 = tid >> 4;
  const float* bP[4];
#pragma unroll
  for (int i = 0; i < 4; ++i) {
    const int row = i * 16 + br0;
    bP[i] = Wout + (size_t)e * DDIM * DFF + (size_t)(n0 + row) * DFF + (tid & 15) * 4;
  }

  const bf16x8 zro = {0, 0, 0, 0, 0, 0, 0, 0};
  const int wid = tid >> 6, lane = tid & 63;
  const int wm = (wid >> 1) * 64;
  const int wn = (wid & 1) * 32;
  const int lr = lane & 15;
  const int lkb = (lane >> 4) * 16;

  f32x4 acc[4][2];
  const f32x4 zf = {0.f, 0.f, 0.f, 0.f};
#pragma unroll
  for (int a = 0; a < 4; ++a) { acc[a][0] = zf; acc[a][1] = zf; }

  bf16x8 aRa[4], aRb[4];
  float4 bRa[4], bRb[4];
  G2_LOAD(aRa, bRa, 0);
  G2_STORE(aRa, bRa, 0);
  G2_LOAD(aRb, bRb, 64);

  for (int kt = 0; kt < 64; ++kt) {
    __syncthreads();
    if (kt < 62) {
      if (kt & 1) G2_LOAD(aRb, bRb, (kt + 2) * 64);
      else        G2_LOAD(aRa, bRa, (kt + 2) * 64);
    }
    const char* Ab = (const char*)Al[kt & 1];
    const char* Bb = (const char*)Bl[kt & 1];
#pragma unroll
    for (int ks = 0; ks < 2; ++ks) {
      bf16x8 a[4], b[2];
      const int kb = ks * 64 + lkb;
#pragma unroll
      for (int fm = 0; fm < 4; ++fm) {
        const int row = wm + fm * 16 + lr;
        a[fm] = *(const bf16x8*)(Ab + ((row * 128 + kb) ^ ((row & 7) << 4)));
      }
#pragma unroll
      for (int ff = 0; ff < 2; ++ff) {
        const int rn = wn + ff * 16 + lr;
        b[ff] = *(const bf16x8*)(Bb + ((rn * 128 + kb) ^ ((rn & 7) << 4)));
      }
#pragma unroll
      for (int fm = 0; fm < 4; ++fm)
#pragma unroll
        for (int ff = 0; ff < 2; ++ff)
          acc[fm][ff] = __builtin_amdgcn_mfma_f32_16x16x32_bf16(a[fm], b[ff], acc[fm][ff], 0, 0, 0);
    }
    if (kt < 63) {
      if (kt & 1) G2_STORE(aRa, bRa, (kt + 1) & 1);
      else        G2_STORE(aRb, bRb, (kt + 1) & 1);
    }
  }

  const int orb = (lane >> 4) * 4;
#pragma unroll
  for (int ff = 0; ff < 2; ++ff) {
    const int ncol = n0 + wn + ff * 16 + lr;
    const float bo = bout[e * DDIM + ncol];
#pragma unroll
    for (int fm = 0; fm < 4; ++fm)
#pragma unroll
      for (int j = 0; j < 4; ++j) {
        const int row = wm + fm * 16 + orb + j;
        if (m0 + row < Me)
          out[(size_t)tokids[row] * DDIM + ncol] = pv[row] * (acc[fm][ff][j] + bo);
      }
  }
}

extern "C" void kernel_launch(void* const* d_in, const int* in_sizes, int n_in,
                              void* d_out, int out_size, void* d_ws, size_t ws_size,
                              hipStream_t stream) {
  const float* hid = (const float*)d_in[0];
  const float* disp = (const float*)d_in[1];
  const float* comb = (const float*)d_in[2];
  const float* Win = (const float*)d_in[3];
  const float* bin = (const float*)d_in[4];
  const float* Wout = (const float*)d_in[5];
  const float* bout = (const float*)d_in[6];
  float* out = (float*)d_out;

  char* ws = (char*)d_ws;
  int* cnt = (int*)(ws);
  int* tokl = (int*)(ws + 256);
  float* scale = (float*)(ws + 256 + NTOK * NEXP * 4);
  short* act = (short*)(ws + (1 << 17));

  route_k<<<1, 256, 0, stream>>>(disp, comb, cnt, tokl, scale);
  gemm1_k<<<dim3(DFF / 64, 4, NEXP), 256, 0, stream>>>(hid, Win, bin, cnt, tokl, act);
  gemm2_k<<<dim3(DDIM / 64, 4, NEXP), 256, 0, stream>>>(act, Wout, bout, cnt, tokl, scale, out);
}

// Round 9
// 234.830 us; speedup vs baseline: 1.1075x; 1.1075x over previous
//
#include <hip/hip_runtime.h>
#include <math.h>

#define NTOK 2048
#define DDIM 1024
#define NEXP 8
#define DFF 4096
#define TWODFF 8192

typedef __attribute__((ext_vector_type(8))) short bf16x8;
typedef __attribute__((ext_vector_type(4))) float f32x4;

__device__ __forceinline__ short f2bf(float f) {
  unsigned u = __builtin_bit_cast(unsigned, f);
  u = (u + 0x7FFFu + ((u >> 16) & 1u)) >> 16;
  return (short)u;
}

// packed f32 pair -> 2x bf16 (D.lo = a, D.hi = b), RTNE
__device__ __forceinline__ unsigned pk2(float a, float b) {
  unsigned r;
  asm("v_cvt_pk_bf16_f32 %0, %1, %2" : "=v"(r) : "v"(a), "v"(b));
  return r;
}

// LDS-only barrier: does NOT drain vmcnt (unlike __syncthreads, which emits
// s_waitcnt vmcnt(0) lgkmcnt(0) and kills any cross-barrier load pipeline).
// Safe here: in-loop cross-wave communication is LDS-only.
__device__ __forceinline__ void ldsbar() {
  asm volatile("s_waitcnt lgkmcnt(0)" ::: "memory");
  __builtin_amdgcn_s_barrier();
}

// ---------------- routing ----------------
__global__ void route_k(const float* __restrict__ disp, const float* __restrict__ comb,
                        int* __restrict__ cnt, int* __restrict__ tokl,
                        float* __restrict__ scale) {
  __shared__ int lcnt[NEXP];
  const int tid = threadIdx.x;
  if (tid < NEXP) lcnt[tid] = 0;
  __syncthreads();
  for (int i = 0; i < 8; ++i) {
    const int t = i * 256 + tid;
    const float* row = disp + (size_t)t * NEXP;
    int e = 0;
#pragma unroll
    for (int n = 1; n < NEXP; ++n) e = (row[n] > row[e]) ? n : e;
    const float p = comb[(size_t)t * NEXP + e];
    const int slot = atomicAdd(&lcnt[e], 1);
    tokl[e * NTOK + slot] = t;
    scale[t] = p;
  }
  __syncthreads();
  if (tid < NEXP) cnt[tid] = lcnt[tid];
}

// ---------------- GEMM1: act = x * gelu(gate), bf16 out ----------------
// BM=128 tok, BNf=64 dual (128 wrows), BK=64 (16 K-steps, 32 MFMA/barrier),
// 4 waves 2m x 2f, 2 LDS buffers, dist-1 reg staging, LDS-only barriers.
#define G1_LOAD(k0) do {                                                      \
  _Pragma("unroll") for (int i_ = 0; i_ < 4; ++i_) {                          \
    sb[i_][0] = *(const float4*)(bP[i_] + (k0));                              \
    sb[i_][1] = *(const float4*)(bP[i_] + (k0) + 4);                          \
    if (aP[i_]) {                                                             \
      sa[i_][0] = *(const float4*)(aP[i_] + (k0));                            \
      sa[i_][1] = *(const float4*)(aP[i_] + (k0) + 4);                        \
    } else {                                                                  \
      sa[i_][0] = make_float4(0.f, 0.f, 0.f, 0.f);                            \
      sa[i_][1] = make_float4(0.f, 0.f, 0.f, 0.f);                            \
    }                                                                         \
  } } while (0)

#define G1_STORE(buf) do {                                                    \
  _Pragma("unroll") for (int i_ = 0; i_ < 4; ++i_) {                          \
    const int row_ = i_ * 32 + r0;                                            \
    const int bo_ = (row_ * 128 + (tid & 7) * 16) ^ ((row_ & 7) << 4);        \
    uint4 va_, vb_;                                                           \
    va_.x = pk2(sa[i_][0].x, sa[i_][0].y); va_.y = pk2(sa[i_][0].z, sa[i_][0].w); \
    va_.z = pk2(sa[i_][1].x, sa[i_][1].y); va_.w = pk2(sa[i_][1].z, sa[i_][1].w); \
    vb_.x = pk2(sb[i_][0].x, sb[i_][0].y); vb_.y = pk2(sb[i_][0].z, sb[i_][0].w); \
    vb_.z = pk2(sb[i_][1].x, sb[i_][1].y); vb_.w = pk2(sb[i_][1].z, sb[i_][1].w); \
    *(uint4*)((char*)Al[buf] + bo_) = va_;                                    \
    *(uint4*)((char*)Bl[buf] + bo_) = vb_;                                    \
  } } while (0)

__global__ __launch_bounds__(256, 2) void gemm1_k(
    const float* __restrict__ hid, const float* __restrict__ Win,
    const float* __restrict__ bin, const int* __restrict__ cnt,
    const int* __restrict__ tokl, short* __restrict__ act) {
  const int e = blockIdx.z;
  const int Me = cnt[e];
  const int m0 = blockIdx.y * 128;
  if (m0 >= Me) return;
  const int f0 = blockIdx.x * 64;

  __shared__ short Al[2][128 * 64];  // 128-B rows, XOR-swizzled
  __shared__ short Bl[2][128 * 64];  // rows 0-63: x(f0..), 64-127: gate
  __shared__ int tokids[128];

  const int tid = threadIdx.x;
  if (tid < 128) {
    const int r = m0 + tid;
    tokids[tid] = (r < Me) ? tokl[e * NTOK + r] : -1;
  }
  __syncthreads();

  // staging: slot i -> row = i*32 + (tid>>3), cols = (tid&7)*8 .. +8 f32
  const int r0 = tid >> 3;
  const int c0 = (tid & 7) * 8;
  const float* aP[4];
  const float* bP[4];
#pragma unroll
  for (int i = 0; i < 4; ++i) {
    const int row = i * 32 + r0;
    const int tk = tokids[row];
    aP[i] = (tk >= 0) ? (hid + (size_t)tk * DDIM + c0) : nullptr;
    const int wr = (row < 64) ? (f0 + row) : (DFF + f0 + (row - 64));
    bP[i] = Win + (size_t)e * TWODFF * DDIM + (size_t)wr * DDIM + c0;
  }

  const int wid = tid >> 6, lane = tid & 63;
  const int wm = (wid >> 1) * 64;
  const int wf = (wid & 1) * 32;
  const int lr = lane & 15;
  const int lkb = (lane >> 4) * 16;

  f32x4 accx[4][2], accg[4][2];
  const f32x4 zf = {0.f, 0.f, 0.f, 0.f};
#pragma unroll
  for (int a = 0; a < 4; ++a)
#pragma unroll
    for (int b = 0; b < 2; ++b) { accx[a][b] = zf; accg[a][b] = zf; }

  float4 sa[4][2], sb[4][2];
  G1_LOAD(0);
  G1_STORE(0);

  for (int kt = 0; kt < 16; ++kt) {
    ldsbar();
    if (kt < 15) G1_LOAD((kt + 1) * 64);  // issue next tile; stays in flight
    const char* Ab = (const char*)Al[kt & 1];
    const char* Bb = (const char*)Bl[kt & 1];
#pragma unroll
    for (int ks = 0; ks < 2; ++ks) {
      const int kb = ks * 64 + lkb;
      bf16x8 a[4], bx[2], bg[2];
#pragma unroll
      for (int fm = 0; fm < 4; ++fm) {
        const int row = wm + fm * 16 + lr;
        a[fm] = *(const bf16x8*)(Ab + ((row * 128 + kb) ^ ((row & 7) << 4)));
      }
#pragma unroll
      for (int ff = 0; ff < 2; ++ff) {
        const int rx = wf + ff * 16 + lr;
        bx[ff] = *(const bf16x8*)(Bb + ((rx * 128 + kb) ^ ((rx & 7) << 4)));
        const int rg = rx + 64;
        bg[ff] = *(const bf16x8*)(Bb + ((rg * 128 + kb) ^ ((rg & 7) << 4)));
      }
#pragma unroll
      for (int fm = 0; fm < 4; ++fm)
#pragma unroll
        for (int ff = 0; ff < 2; ++ff) {
          accx[fm][ff] = __builtin_amdgcn_mfma_f32_16x16x32_bf16(a[fm], bx[ff], accx[fm][ff], 0, 0, 0);
          accg[fm][ff] = __builtin_amdgcn_mfma_f32_16x16x32_bf16(a[fm], bg[ff], accg[fm][ff], 0, 0, 0);
        }
    }
    if (kt < 15) G1_STORE((kt + 1) & 1);  // counted vmcnt wait, not a drain
  }

  const int orb = (lane >> 4) * 4;
#pragma unroll
  for (int ff = 0; ff < 2; ++ff) {
    const int fcol = f0 + wf + ff * 16 + lr;
    const float bx_ = bin[e * TWODFF + fcol];
    const float bg_ = bin[e * TWODFF + DFF + fcol];
#pragma unroll
    for (int fm = 0; fm < 4; ++fm)
#pragma unroll
      for (int j = 0; j < 4; ++j) {
        const int row = wm + fm * 16 + orb + j;
        if (m0 + row < Me) {
          const float x = accx[fm][ff][j] + bx_;
          const float g = accg[fm][ff][j] + bg_;
          const float gl = 0.5f * g * (1.f + erff(g * 0.70710678118654752f));
          act[(size_t)tokids[row] * DFF + fcol] = f2bf(x * gl);
        }
      }
  }
}

// ---------------- GEMM2: out = p * (act @ W_out^T + b_out) ----------------
// r8 dist-2 structure, barriers swapped to LDS-only.
#define G2_LOAD(aR, bR, k0) do {                                              \
  _Pragma("unroll") for (int i_ = 0; i_ < 4; ++i_)                            \
    bR[i_] = *(const float4*)(bP[i_] + (k0));                                 \
  _Pragma("unroll") for (int i_ = 0; i_ < 4; ++i_)                            \
    aR[i_] = aP[i_] ? *(const bf16x8*)(aP[i_] + (k0)) : zro;                  \
  } while (0)

#define G2_STORE(aR, bR, buf) do {                                            \
  _Pragma("unroll") for (int i_ = 0; i_ < 4; ++i_) {                          \
    const int row_ = i_ * 32 + ar0;                                           \
    const int ba_ = (row_ * 128 + (tid & 7) * 16) ^ ((row_ & 7) << 4);        \
    *(bf16x8*)((char*)Al[buf] + ba_) = aR[i_];                                \
  }                                                                           \
  _Pragma("unroll") for (int i_ = 0; i_ < 4; ++i_) {                          \
    const int row_ = i_ * 16 + br0;                                           \
    const int bb_ = (row_ * 128 + (tid & 15) * 8) ^ ((row_ & 7) << 4);        \
    uint2 vb_;                                                                \
    vb_.x = pk2(bR[i_].x, bR[i_].y); vb_.y = pk2(bR[i_].z, bR[i_].w);         \
    *(uint2*)((char*)Bl[buf] + bb_) = vb_;                                    \
  } } while (0)

__global__ __launch_bounds__(256, 2) void gemm2_k(
    const short* __restrict__ act, const float* __restrict__ Wout,
    const float* __restrict__ bout, const int* __restrict__ cnt,
    const int* __restrict__ tokl, const float* __restrict__ scale,
    float* __restrict__ out) {
  const int e = blockIdx.z;
  const int Me = cnt[e];
  const int m0 = blockIdx.y * 128;
  if (m0 >= Me) return;
  const int n0 = blockIdx.x * 64;

  __shared__ short Al[2][128 * 64];
  __shared__ short Bl[2][64 * 64];
  __shared__ int tokids[128];
  __shared__ float pv[128];

  const int tid = threadIdx.x;
  if (tid < 128) {
    const int r = m0 + tid;
    const int tk = (r < Me) ? tokl[e * NTOK + r] : -1;
    tokids[tid] = tk;
    pv[tid] = (tk >= 0) ? scale[tk] : 0.f;
  }
  __syncthreads();

  const int ar0 = tid >> 3;
  const int ac0 = (tid & 7) * 8;
  const short* aP[4];
#pragma unroll
  for (int i = 0; i < 4; ++i) {
    const int row = i * 32 + ar0;
    const int tk = tokids[row];
    aP[i] = (tk >= 0) ? (act + (size_t)tk * DFF + ac0) : nullptr;
  }
  const int br0 = tid >> 4;
  const float* bP[4];
#pragma unroll
  for (int i = 0; i < 4; ++i) {
    const int row = i * 16 + br0;
    bP[i] = Wout + (size_t)e * DDIM * DFF + (size_t)(n0 + row) * DFF + (tid & 15) * 4;
  }

  const bf16x8 zro = {0, 0, 0, 0, 0, 0, 0, 0};
  const int wid = tid >> 6, lane = tid & 63;
  const int wm = (wid >> 1) * 64;
  const int wn = (wid & 1) * 32;
  const int lr = lane & 15;
  const int lkb = (lane >> 4) * 16;

  f32x4 acc[4][2];
  const f32x4 zf = {0.f, 0.f, 0.f, 0.f};
#pragma unroll
  for (int a = 0; a < 4; ++a) { acc[a][0] = zf; acc[a][1] = zf; }

  bf16x8 aRa[4], aRb[4];
  float4 bRa[4], bRb[4];
  G2_LOAD(aRa, bRa, 0);
  G2_STORE(aRa, bRa, 0);
  G2_LOAD(aRb, bRb, 64);

  for (int kt = 0; kt < 64; ++kt) {
    ldsbar();
    if (kt < 62) {
      if (kt & 1) G2_LOAD(aRb, bRb, (kt + 2) * 64);
      else        G2_LOAD(aRa, bRa, (kt + 2) * 64);
    }
    const char* Ab = (const char*)Al[kt & 1];
    const char* Bb = (const char*)Bl[kt & 1];
#pragma unroll
    for (int ks = 0; ks < 2; ++ks) {
      bf16x8 a[4], b[2];
      const int kb = ks * 64 + lkb;
#pragma unroll
      for (int fm = 0; fm < 4; ++fm) {
        const int row = wm + fm * 16 + lr;
        a[fm] = *(const bf16x8*)(Ab + ((row * 128 + kb) ^ ((row & 7) << 4)));
      }
#pragma unroll
      for (int ff = 0; ff < 2; ++ff) {
        const int rn = wn + ff * 16 + lr;
        b[ff] = *(const bf16x8*)(Bb + ((rn * 128 + kb) ^ ((rn & 7) << 4)));
      }
#pragma unroll
      for (int fm = 0; fm < 4; ++fm)
#pragma unroll
        for (int ff = 0; ff < 2; ++ff)
          acc[fm][ff] = __builtin_amdgcn_mfma_f32_16x16x32_bf16(a[fm], b[ff], acc[fm][ff], 0, 0, 0);
    }
    if (kt < 63) {
      if (kt & 1) G2_STORE(aRa, bRa, (kt + 1) & 1);
      else        G2_STORE(aRb, bRb, (kt + 1) & 1);
    }
  }

  const int orb = (lane >> 4) * 4;
#pragma unroll
  for (int ff = 0; ff < 2; ++ff) {
    const int ncol = n0 + wn + ff * 16 + lr;
    const float bo = bout[e * DDIM + ncol];
#pragma unroll
    for (int fm = 0; fm < 4; ++fm)
#pragma unroll
      for (int j = 0; j < 4; ++j) {
        const int row = wm + fm * 16 + orb + j;
        if (m0 + row < Me)
          out[(size_t)tokids[row] * DDIM + ncol] = pv[row] * (acc[fm][ff][j] + bo);
      }
  }
}

extern "C" void kernel_launch(void* const* d_in, const int* in_sizes, int n_in,
                              void* d_out, int out_size, void* d_ws, size_t ws_size,
                              hipStream_t stream) {
  const float* hid = (const float*)d_in[0];
  const float* disp = (const float*)d_in[1];
  const float* comb = (const float*)d_in[2];
  const float* Win = (const float*)d_in[3];
  const float* bin = (const float*)d_in[4];
  const float* Wout = (const float*)d_in[5];
  const float* bout = (const float*)d_in[6];
  float* out = (float*)d_out;

  char* ws = (char*)d_ws;
  int* cnt = (int*)(ws);
  int* tokl = (int*)(ws + 256);
  float* scale = (float*)(ws + 256 + NTOK * NEXP * 4);
  short* act = (short*)(ws + (1 << 17));

  route_k<<<1, 256, 0, stream>>>(disp, comb, cnt, tokl, scale);
  gemm1_k<<<dim3(DFF / 64, 4, NEXP), 256, 0, stream>>>(hid, Win, bin, cnt, tokl, act);
  gemm2_k<<<dim3(DDIM / 64, 4, NEXP), 256, 0, stream>>>(act, Wout, bout, cnt, tokl, scale, out);
}